// Round 21
// baseline (69.447 us; speedup 1.0000x reference)
//
#include <hip/hip_runtime.h>
#include <hip/hip_bf16.h>

typedef __attribute__((ext_vector_type(8))) short bf16x8;
typedef __attribute__((ext_vector_type(4))) float f32x4;

__device__ __forceinline__ unsigned int pk2(float a, float b) {
  union { __hip_bfloat162 h; unsigned int u; } cv;
  cv.h = __float22bfloat162_rn(make_float2(a, b));   // v_cvt_pk_bf16_f32
  return cv.u;
}
__device__ __forceinline__ unsigned short f2bf(float f) {
  unsigned int u = __float_as_uint(f);
  u += 0x7FFFu + ((u >> 16) & 1u);
  return (unsigned short)(u >> 16);
}

// DPP quad-perm cross-lane (VALU) for xor1/xor2 butterfly stages.
__device__ __forceinline__ float dpp_xor1(float v) {
  return __int_as_float(__builtin_amdgcn_update_dpp(
      0, __float_as_int(v), 0xB1, 0xF, 0xF, true));
}
__device__ __forceinline__ float dpp_xor2(float v) {
  return __int_as_float(__builtin_amdgcn_update_dpp(
      0, __float_as_int(v), 0x4E, 0xF, 0xF, true));
}

// qw[n][e] = (scale*0.5) * sum_d query[n][d] * W[d][e]; entmax pre-scale 0.5
// folded in (power-of-2: bit-exact bf16 mantissas). Two accs halve the chain.
__global__ void __launch_bounds__(256) qw_kernel(const float* __restrict__ q,
                                                 const float* __restrict__ W,
                                                 unsigned short* __restrict__ qw) {
  int n = blockIdx.x, e = threadIdx.x;
  float acc0 = 0.f, acc1 = 0.f;
  #pragma unroll 16
  for (int d = 0; d < 256; d += 2) {
    acc0 = fmaf(q[n * 256 + d],     W[d * 256 + e],       acc0);
    acc1 = fmaf(q[n * 256 + d + 1], W[(d + 1) * 256 + e], acc1);
  }
  qw[n * 256 + e] = f2bf((acc0 + acc1) * 0.03125f);  // 256^-0.5 * 0.5
}

// One block per batch b. 512 threads = 8 waves.  (R20 structure, best = 67.1us.)
// R21: staging ILP isolated — all 8 dwordx4 loads issued before any convert,
// pinned with sched_barrier(0) (within-phase, no barrier crossed, no spill:
// ~72 VGPR < 85 budget at 6 waves/EU). Everything else identical to R20.
__global__ void __launch_bounds__(512, 6) cross_main(
    const float* __restrict__ x, const float* __restrict__ value,
    const unsigned short* __restrict__ qw, float* __restrict__ out) {

  __shared__ __align__(16) unsigned short lds_x[64 * 268];       // x[f][e] bf16, row = 536 B
  __shared__ __align__(16) unsigned char  lds_pool[64 * 68 * 4]; // att (f32) then aw (bf16)

  float* lds_att = (float*)lds_pool;                  // [64][68] f32: GEMM1 -> entmax
  unsigned short* lds_aw = (unsigned short*)lds_pool; // [64][72] bf16: entmax -> GEMM2

  const int t = threadIdx.x;
  const int b = blockIdx.x;
  const int l = t & 63;
  const int w = t >> 6;
  const int l15 = l & 15, l4 = l >> 4;

  // ---- prologue: hoist batch-invariant value row (hides under stage+GEMM1) ----
  const int n_ent = w * 8 + (l >> 3);      // entmax row for this thread
  const int fb_ent = (l & 7) * 8;          // 8 f's per lane
  const float4 va = *(const float4*)(value + n_ent * 64 + fb_ent);
  const float4 vb = *(const float4*)(value + n_ent * 64 + fb_ent + 4);

  // ---- stage x[b]: ALL 8 loads in flight, then convert (sched_barrier pins) ----
  {
    const float4* xg = (const float4*)(x + (size_t)b * 16384);
    float4 v[8];
    #pragma unroll
    for (int it = 0; it < 4; ++it) {
      v[2 * it]     = xg[2 * (it * 512 + t)];
      v[2 * it + 1] = xg[2 * (it * 512 + t) + 1];
    }
    __builtin_amdgcn_sched_barrier(0);   // keep all 8 loads issued before converts
    #pragma unroll
    for (int it = 0; it < 4; ++it) {
      int u = it * 512 + t;              // 8-float unit, 0..2047
      int f = u >> 5, c8 = u & 31;
      char* dst = (char*)lds_x + f * 536 + c8 * 16;   // 8-aligned
      *(uint2*)dst       = make_uint2(pk2(v[2*it].x, v[2*it].y), pk2(v[2*it].z, v[2*it].w));
      *(uint2*)(dst + 8) = make_uint2(pk2(v[2*it+1].x, v[2*it+1].y), pk2(v[2*it+1].z, v[2*it+1].w));
    }
  }
  __syncthreads();

  // ---- att[n][f] = sum_e qw[n][e] * x[f][e]  (M=n, N=f, K=e) ----
  {
    int nt = w >> 1, ft0 = (w & 1) * 2;    // wave tile: 1 n-tile x 2 f-tiles
    f32x4 acc0 = {0.f, 0.f, 0.f, 0.f}, acc1 = {0.f, 0.f, 0.f, 0.f};
    const unsigned short* qa = qw + (nt * 16 + l15) * 256 + l4 * 8;
    const char* rb0 = (const char*)lds_x + (ft0 * 16 + l15) * 536 + l4 * 16;
    const char* rb1 = rb0 + 16 * 536;
    #pragma unroll
    for (int kc = 0; kc < 8; ++kc) {
      union BF { uint2 d[2]; bf16x8 v; };
      bf16x8 a = *(const bf16x8*)(qa + kc * 32);       // global (L1/L2-resident)
      BF b0, b1;
      b0.d[0] = *(const uint2*)(rb0 + kc * 64);
      b0.d[1] = *(const uint2*)(rb0 + kc * 64 + 8);
      b1.d[0] = *(const uint2*)(rb1 + kc * 64);
      b1.d[1] = *(const uint2*)(rb1 + kc * 64 + 8);
      acc0 = __builtin_amdgcn_mfma_f32_16x16x32_bf16(a, b0.v, acc0, 0, 0, 0);
      acc1 = __builtin_amdgcn_mfma_f32_16x16x32_bf16(a, b1.v, acc1, 0, 0, 0);
    }
    int nrow = nt * 16 + 4 * l4;
    #pragma unroll
    for (int r = 0; r < 4; ++r) {
      lds_att[(nrow + r) * 68 + ft0 * 16 + l15]       = acc0[r];
      lds_att[(nrow + r) * 68 + (ft0 + 1) * 16 + l15] = acc1[r];
    }
  }
  __syncthreads();

  // ---- entmax15 over f per row (8 lanes/row); aw[n][f] = gate * value[n][f] ----
  {
    f32x4 z0 = *(const f32x4*)&lds_att[n_ent * 68 + fb_ent];
    f32x4 z1 = *(const f32x4*)&lds_att[n_ent * 68 + fb_ent + 4];
    __syncthreads();                // att dead; aw may overwrite pool
    float z[8];
    #pragma unroll
    for (int k = 0; k < 4; ++k) { z[k] = z0[k]; z[k + 4] = z1[k]; }  // 0.5 folded in qw
    float m = fmaxf(fmaxf(fmaxf(z[0], z[1]), fmaxf(z[2], z[3])),
                    fmaxf(fmaxf(z[4], z[5]), fmaxf(z[6], z[7])));
    m = fmaxf(m, dpp_xor1(m));
    m = fmaxf(m, dpp_xor2(m));
    m = fmaxf(m, __shfl_xor(m, 4));
    // Newton on f(tau) = sum (z-tau)_+^2 - 1: convex decreasing, start at
    // bracket-lo (f>=0) => monotone from below, quadratic endgame.
    float tau = m - 1.0f;
    #pragma unroll
    for (int it = 0; it < 8; ++it) {
      float s0 = 0.f, s1 = 0.f, q0 = 0.f, q1 = 0.f;
      #pragma unroll
      for (int k = 0; k < 4; ++k) {
        float d0 = fmaxf(z[k] - tau, 0.f);
        float d1 = fmaxf(z[k + 4] - tau, 0.f);
        s0 = fmaf(d0, d0, s0); q0 += d0;
        s1 = fmaf(d1, d1, s1); q1 += d1;
      }
      float s = s0 + s1, q = q0 + q1;
      s += dpp_xor1(s); s += dpp_xor2(s); s += __shfl_xor(s, 4);
      q += dpp_xor1(q); q += dpp_xor2(q); q += __shfl_xor(q, 4);
      tau += (s - 1.0f) * 0.5f * __builtin_amdgcn_rcpf(q);
    }
    float p[8]; float S = 0.f;
    #pragma unroll
    for (int k = 0; k < 8; ++k) { float d = fmaxf(z[k] - tau, 0.f); p[k] = d * d; S += p[k]; }
    S += dpp_xor1(S); S += dpp_xor2(S); S += __shfl_xor(S, 4);
    float invS = 1.0f / S;
    uint4 pkv;
    pkv.x = pk2(p[0] * invS * va.x, p[1] * invS * va.y);
    pkv.y = pk2(p[2] * invS * va.z, p[3] * invS * va.w);
    pkv.z = pk2(p[4] * invS * vb.x, p[5] * invS * vb.y);
    pkv.w = pk2(p[6] * invS * vb.z, p[7] * invS * vb.w);
    *(uint4*)&lds_aw[n_ent * 72 + fb_ent] = pkv;   // 16B-aligned
  }
  __syncthreads();

  // ---- out[n][e] = exp( sum_f aw[n][f] * x[f][e] ), computed as D[e][n] =
  // mfma(A = x^T frag, B = aw frag): lane's 4 acc values are 4 CONSECUTIVE e
  // -> coalesced dwordx4 stores.
  {
    const int te0 = 2 * w;
    f32x4 acc[2][4];                 // [e-tile j][n-tile nt2]
    #pragma unroll
    for (int j = 0; j < 2; ++j)
      #pragma unroll
      for (int nt2 = 0; nt2 < 4; ++nt2) acc[j][nt2] = (f32x4){0.f, 0.f, 0.f, 0.f};
    #pragma unroll
    for (int kc = 0; kc < 2; ++kc) {
      bf16x8 bfrag[4];               // aw[n=l15][f=kc*32+l4*8..]: contiguous b128
      #pragma unroll
      for (int nt2 = 0; nt2 < 4; ++nt2)
        bfrag[nt2] = *(const bf16x8*)&lds_aw[(nt2 * 16 + l15) * 72 + kc * 32 + l4 * 8];
      const char* gp = (const char*)lds_x + (kc * 32 + l4 * 8) * 536 + (te0 * 16 + l15) * 2;
      #pragma unroll
      for (int j = 0; j < 2; ++j) {
        union { unsigned short u[8]; bf16x8 v; } aa;   // x^T gather (2-way, free)
        #pragma unroll
        for (int i = 0; i < 8; ++i)
          aa.u[i] = *(const unsigned short*)(gp + i * 536 + j * 32);
        #pragma unroll
        for (int nt2 = 0; nt2 < 4; ++nt2)
          acc[j][nt2] = __builtin_amdgcn_mfma_f32_16x16x32_bf16(aa.v, bfrag[nt2], acc[j][nt2], 0, 0, 0);
      }
    }
    float* ob = out + (size_t)b * 16384;
    #pragma unroll
    for (int j = 0; j < 2; ++j) {
      #pragma unroll
      for (int nt2 = 0; nt2 < 4; ++nt2) {
        float4 o;
        o.x = __expf(acc[j][nt2][0]);
        o.y = __expf(acc[j][nt2][1]);
        o.z = __expf(acc[j][nt2][2]);
        o.w = __expf(acc[j][nt2][3]);
        // n = nt2*16 + l15, e = (te0+j)*16 + 4*l4 + r (r contiguous)
        *(float4*)&ob[(nt2 * 16 + l15) * 256 + (te0 + j) * 16 + 4 * l4] = o;
      }
    }
  }
}

extern "C" void kernel_launch(void* const* d_in, const int* in_sizes, int n_in,
                              void* d_out, int out_size, void* d_ws, size_t ws_size,
                              hipStream_t stream) {
  const float* x     = (const float*)d_in[0];
  const float* W     = (const float*)d_in[1];
  const float* q     = (const float*)d_in[2];
  const float* value = (const float*)d_in[3];
  float* out = (float*)d_out;
  unsigned short* qw = (unsigned short*)d_ws;  // 64*256 bf16 = 32 KB scratch

  qw_kernel<<<dim3(64), dim3(256), 0, stream>>>(q, W, qw);
  cross_main<<<dim3(2048), dim3(512), 0, stream>>>(x, value, qw, out);
}

// Round 22
// 66.800 us; speedup vs baseline: 1.0396x; 1.0396x over previous
//
#include <hip/hip_runtime.h>
#include <hip/hip_bf16.h>

typedef __attribute__((ext_vector_type(8))) short bf16x8;
typedef __attribute__((ext_vector_type(4))) float f32x4;

__device__ __forceinline__ unsigned int pk2(float a, float b) {
  union { __hip_bfloat162 h; unsigned int u; } cv;
  cv.h = __float22bfloat162_rn(make_float2(a, b));   // v_cvt_pk_bf16_f32
  return cv.u;
}
__device__ __forceinline__ unsigned short f2bf(float f) {
  unsigned int u = __float_as_uint(f);
  u += 0x7FFFu + ((u >> 16) & 1u);
  return (unsigned short)(u >> 16);
}

// DPP quad-perm cross-lane (VALU) for xor1/xor2 butterfly stages.
__device__ __forceinline__ float dpp_xor1(float v) {
  return __int_as_float(__builtin_amdgcn_update_dpp(
      0, __float_as_int(v), 0xB1, 0xF, 0xF, true));
}
__device__ __forceinline__ float dpp_xor2(float v) {
  return __int_as_float(__builtin_amdgcn_update_dpp(
      0, __float_as_int(v), 0x4E, 0xF, 0xF, true));
}

// qw[n][e] = (scale*0.5) * sum_d query[n][d] * W[d][e]; entmax pre-scale 0.5
// folded in (power-of-2: bit-exact bf16 mantissas). Two accs halve the chain.
__global__ void __launch_bounds__(256) qw_kernel(const float* __restrict__ q,
                                                 const float* __restrict__ W,
                                                 unsigned short* __restrict__ qw) {
  int n = blockIdx.x, e = threadIdx.x;
  float acc0 = 0.f, acc1 = 0.f;
  #pragma unroll 16
  for (int d = 0; d < 256; d += 2) {
    acc0 = fmaf(q[n * 256 + d],     W[d * 256 + e],       acc0);
    acc1 = fmaf(q[n * 256 + d + 1], W[(d + 1) * 256 + e], acc1);
  }
  qw[n * 256 + e] = f2bf((acc0 + acc1) * 0.03125f);  // 256^-0.5 * 0.5
}

// One block per batch b. 512 threads = 8 waves.  (R20 structure, session best
// = 67.1us.) Final state: all measured wins kept (retile, stride-268, DPP
// reductions, Newton-8, coalesced D[e][n] stores, folded scales, hoisted
// value loads); all structural departures measured and reverted.
__global__ void __launch_bounds__(512, 6) cross_main(
    const float* __restrict__ x, const float* __restrict__ value,
    const unsigned short* __restrict__ qw, float* __restrict__ out) {

  __shared__ __align__(16) unsigned short lds_x[64 * 268];       // x[f][e] bf16, row = 536 B
  __shared__ __align__(16) unsigned char  lds_pool[64 * 68 * 4]; // att (f32) then aw (bf16)

  float* lds_att = (float*)lds_pool;                  // [64][68] f32: GEMM1 -> entmax
  unsigned short* lds_aw = (unsigned short*)lds_pool; // [64][72] bf16: entmax -> GEMM2

  const int t = threadIdx.x;
  const int b = blockIdx.x;
  const int l = t & 63;
  const int w = t >> 6;
  const int l15 = l & 15, l4 = l >> 4;

  // ---- prologue: hoist batch-invariant value row (hides under stage+GEMM1) ----
  const int n_ent = w * 8 + (l >> 3);      // entmax row for this thread
  const int fb_ent = (l & 7) * 8;          // 8 f's per lane
  const float4 va = *(const float4*)(value + n_ent * 64 + fb_ent);
  const float4 vb = *(const float4*)(value + n_ent * 64 + fb_ent + 4);

  // ---- stage x[b] (fp32 global) -> bf16 LDS via cvt_pk; 8 floats/thread/iter ----
  {
    const float4* xg = (const float4*)(x + (size_t)b * 16384);
    #pragma unroll
    for (int it = 0; it < 4; ++it) {
      int u = it * 512 + t;            // 8-float unit, 0..2047
      float4 v0 = xg[2 * u], v1 = xg[2 * u + 1];
      int f = u >> 5, c8 = u & 31;
      char* dst = (char*)lds_x + f * 536 + c8 * 16;   // 8-aligned
      *(uint2*)dst       = make_uint2(pk2(v0.x, v0.y), pk2(v0.z, v0.w));
      *(uint2*)(dst + 8) = make_uint2(pk2(v1.x, v1.y), pk2(v1.z, v1.w));
    }
  }
  __syncthreads();

  // ---- att[n][f] = sum_e qw[n][e] * x[f][e]  (M=n, N=f, K=e) ----
  {
    int nt = w >> 1, ft0 = (w & 1) * 2;    // wave tile: 1 n-tile x 2 f-tiles
    f32x4 acc0 = {0.f, 0.f, 0.f, 0.f}, acc1 = {0.f, 0.f, 0.f, 0.f};
    const unsigned short* qa = qw + (nt * 16 + l15) * 256 + l4 * 8;
    const char* rb0 = (const char*)lds_x + (ft0 * 16 + l15) * 536 + l4 * 16;
    const char* rb1 = rb0 + 16 * 536;
    #pragma unroll
    for (int kc = 0; kc < 8; ++kc) {
      union BF { uint2 d[2]; bf16x8 v; };
      bf16x8 a = *(const bf16x8*)(qa + kc * 32);       // global (L1/L2-resident)
      BF b0, b1;
      b0.d[0] = *(const uint2*)(rb0 + kc * 64);
      b0.d[1] = *(const uint2*)(rb0 + kc * 64 + 8);
      b1.d[0] = *(const uint2*)(rb1 + kc * 64);
      b1.d[1] = *(const uint2*)(rb1 + kc * 64 + 8);
      acc0 = __builtin_amdgcn_mfma_f32_16x16x32_bf16(a, b0.v, acc0, 0, 0, 0);
      acc1 = __builtin_amdgcn_mfma_f32_16x16x32_bf16(a, b1.v, acc1, 0, 0, 0);
    }
    int nrow = nt * 16 + 4 * l4;
    #pragma unroll
    for (int r = 0; r < 4; ++r) {
      lds_att[(nrow + r) * 68 + ft0 * 16 + l15]       = acc0[r];
      lds_att[(nrow + r) * 68 + (ft0 + 1) * 16 + l15] = acc1[r];
    }
  }
  __syncthreads();

  // ---- entmax15 over f per row (8 lanes/row); aw[n][f] = gate * value[n][f] ----
  {
    f32x4 z0 = *(const f32x4*)&lds_att[n_ent * 68 + fb_ent];
    f32x4 z1 = *(const f32x4*)&lds_att[n_ent * 68 + fb_ent + 4];
    __syncthreads();                // att dead; aw may overwrite pool
    float z[8];
    #pragma unroll
    for (int k = 0; k < 4; ++k) { z[k] = z0[k]; z[k + 4] = z1[k]; }  // 0.5 folded in qw
    float m = fmaxf(fmaxf(fmaxf(z[0], z[1]), fmaxf(z[2], z[3])),
                    fmaxf(fmaxf(z[4], z[5]), fmaxf(z[6], z[7])));
    m = fmaxf(m, dpp_xor1(m));
    m = fmaxf(m, dpp_xor2(m));
    m = fmaxf(m, __shfl_xor(m, 4));
    // Newton on f(tau) = sum (z-tau)_+^2 - 1: convex decreasing, start at
    // bracket-lo (f>=0) => monotone from below, quadratic endgame.
    float tau = m - 1.0f;
    #pragma unroll
    for (int it = 0; it < 8; ++it) {
      float s0 = 0.f, s1 = 0.f, q0 = 0.f, q1 = 0.f;
      #pragma unroll
      for (int k = 0; k < 4; ++k) {
        float d0 = fmaxf(z[k] - tau, 0.f);
        float d1 = fmaxf(z[k + 4] - tau, 0.f);
        s0 = fmaf(d0, d0, s0); q0 += d0;
        s1 = fmaf(d1, d1, s1); q1 += d1;
      }
      float s = s0 + s1, q = q0 + q1;
      s += dpp_xor1(s); s += dpp_xor2(s); s += __shfl_xor(s, 4);
      q += dpp_xor1(q); q += dpp_xor2(q); q += __shfl_xor(q, 4);
      tau += (s - 1.0f) * 0.5f * __builtin_amdgcn_rcpf(q);
    }
    float p[8]; float S = 0.f;
    #pragma unroll
    for (int k = 0; k < 8; ++k) { float d = fmaxf(z[k] - tau, 0.f); p[k] = d * d; S += p[k]; }
    S += dpp_xor1(S); S += dpp_xor2(S); S += __shfl_xor(S, 4);
    float invS = 1.0f / S;
    uint4 pkv;
    pkv.x = pk2(p[0] * invS * va.x, p[1] * invS * va.y);
    pkv.y = pk2(p[2] * invS * va.z, p[3] * invS * va.w);
    pkv.z = pk2(p[4] * invS * vb.x, p[5] * invS * vb.y);
    pkv.w = pk2(p[6] * invS * vb.z, p[7] * invS * vb.w);
    *(uint4*)&lds_aw[n_ent * 72 + fb_ent] = pkv;   // 16B-aligned
  }
  __syncthreads();

  // ---- out[n][e] = exp( sum_f aw[n][f] * x[f][e] ), computed as D[e][n] =
  // mfma(A = x^T frag, B = aw frag): lane's 4 acc values are 4 CONSECUTIVE e
  // -> coalesced dwordx4 stores.
  {
    const int te0 = 2 * w;
    f32x4 acc[2][4];                 // [e-tile j][n-tile nt2]
    #pragma unroll
    for (int j = 0; j < 2; ++j)
      #pragma unroll
      for (int nt2 = 0; nt2 < 4; ++nt2) acc[j][nt2] = (f32x4){0.f, 0.f, 0.f, 0.f};
    #pragma unroll
    for (int kc = 0; kc < 2; ++kc) {
      bf16x8 bfrag[4];               // aw[n=l15][f=kc*32+l4*8..]: contiguous b128
      #pragma unroll
      for (int nt2 = 0; nt2 < 4; ++nt2)
        bfrag[nt2] = *(const bf16x8*)&lds_aw[(nt2 * 16 + l15) * 72 + kc * 32 + l4 * 8];
      const char* gp = (const char*)lds_x + (kc * 32 + l4 * 8) * 536 + (te0 * 16 + l15) * 2;
      #pragma unroll
      for (int j = 0; j < 2; ++j) {
        union { unsigned short u[8]; bf16x8 v; } aa;   // x^T gather (2-way, free)
        #pragma unroll
        for (int i = 0; i < 8; ++i)
          aa.u[i] = *(const unsigned short*)(gp + i * 536 + j * 32);
        #pragma unroll
        for (int nt2 = 0; nt2 < 4; ++nt2)
          acc[j][nt2] = __builtin_amdgcn_mfma_f32_16x16x32_bf16(aa.v, bfrag[nt2], acc[j][nt2], 0, 0, 0);
      }
    }
    float* ob = out + (size_t)b * 16384;
    #pragma unroll
    for (int j = 0; j < 2; ++j) {
      #pragma unroll
      for (int nt2 = 0; nt2 < 4; ++nt2) {
        float4 o;
        o.x = __expf(acc[j][nt2][0]);
        o.y = __expf(acc[j][nt2][1]);
        o.z = __expf(acc[j][nt2][2]);
        o.w = __expf(acc[j][nt2][3]);
        // n = nt2*16 + l15, e = (te0+j)*16 + 4*l4 + r (r contiguous)
        *(float4*)&ob[(nt2 * 16 + l15) * 256 + (te0 + j) * 16 + 4 * l4] = o;
      }
    }
  }
}

extern "C" void kernel_launch(void* const* d_in, const int* in_sizes, int n_in,
                              void* d_out, int out_size, void* d_ws, size_t ws_size,
                              hipStream_t stream) {
  const float* x     = (const float*)d_in[0];
  const float* W     = (const float*)d_in[1];
  const float* q     = (const float*)d_in[2];
  const float* value = (const float*)d_in[3];
  float* out = (float*)d_out;
  unsigned short* qw = (unsigned short*)d_ws;  // 64*256 bf16 = 32 KB scratch

  qw_kernel<<<dim3(64), dim3(256), 0, stream>>>(q, W, qw);
  cross_main<<<dim3(2048), dim3(512), 0, stream>>>(x, value, qw, out);
}